// Round 2
// baseline (304.333 us; speedup 1.0000x reference)
//
#include <hip/hip_runtime.h>
#include <hip/hip_bf16.h>
#include <cstdint>

#define NQ 256
#define NK 2048
#define BB 2
#define SCALE 0.17677669529663687f  // 32^-0.5

// ws byte offsets (16B aligned)
#define TB_OFF 0u         // ushort[64000]  bf16 tables [i][z][y][x][h]   128000 B
#define QP_OFF 128000u    // float[131072]  q-proj (B,nQ,256), pre-scaled 524288 B
#define KT_OFF 652288u    // float[131072]  k-proj transposed (B,32,nK)   524288 B
#define VP_OFF 1176576u   // float[131072]  v-proj (B,nK,32)              524288 B
#define X_OFF  1700864u   // float[131072]  x = attn@v, [b][q][256]       524288 B

typedef unsigned short u16;

static __device__ __forceinline__ float blo(uint32_t u) { return __uint_as_float(u << 16); }
static __device__ __forceinline__ float bhi(uint32_t u) { return __uint_as_float(u & 0xffff0000u); }

static __device__ __forceinline__ u16 f2bf(float f) {
  union { float f; uint32_t u; } v; v.f = f;
  uint32_t r = (v.u + 0x7fffu + ((v.u >> 16) & 1u)) >> 16;
  return (u16)r;
}

// ---------------- kernel 0: fused prep (tables + kv-proj + q-proj) ----------------
// blocks [0,256): kv-proj   [256,320): q-proj   [320,328): cpb tables
__global__ __launch_bounds__(512) void k_prep(const float* __restrict__ query,
                                              const float* __restrict__ key,
                                              const float* __restrict__ qw,
                                              const float* __restrict__ qb,
                                              const float* __restrict__ kw,
                                              const float* __restrict__ kb,
                                              const float* __restrict__ vw,
                                              const float* __restrict__ vb,
                                              const float* __restrict__ w1g,
                                              const float* __restrict__ b1g,
                                              const float* __restrict__ w2g,
                                              u16* __restrict__ tb,
                                              float* __restrict__ qp,
                                              float* __restrict__ kpT,
                                              float* __restrict__ vp) {
  __shared__ __align__(16) char smraw[16 * 257 * 4];
  int bid = blockIdx.x, t = threadIdx.x;

  if (bid < 256) {
    // ---- kv-proj: kpT[b][d][k], vp[b][k][d] ----
    float (*rows)[257] = (float(*)[257])smraw;
    int b = bid >> 7, kc = bid & 127;
    for (int idx = t; idx < 4096; idx += 512) {
      int r = idx >> 8, m = idx & 255;
      rows[r][m] = key[((kc * 16 + r) * BB + b) * 256 + m];
    }
    __syncthreads();
    int ks = t >> 5, d = t & 31;
    float a = kb[d], av = vb[d];
    #pragma unroll 4
    for (int m = 0; m < 256; ++m) {
      float rv = rows[ks][m];
      a  = fmaf(rv, kw[m * 32 + d], a);
      av = fmaf(rv, vw[m * 32 + d], av);
    }
    int k = kc * 16 + ks;
    kpT[(b * 32 + d) * NK + k] = a;
    vp[(b * NK + k) * 32 + d] = av;
  } else if (bid < 320) {
    // ---- q-proj (pre-scaled): 8 rows per block ----
    float (*rows)[257] = (float(*)[257])smraw;
    int qg = bid - 256;  // 0..63, 8 global rows each
    for (int idx = t; idx < 2048; idx += 512) {
      int r = idx >> 8, m = idx & 255;
      int g = qg * 8 + r, b = g >> 8, q = g & 255;
      rows[r][m] = query[(q * BB + b) * 256 + m];
    }
    __syncthreads();
    int r = t >> 6, c0 = (t & 63) * 4;
    int g = qg * 8 + r;
    float4 acc = *(const float4*)&qb[c0];
    #pragma unroll 4
    for (int m = 0; m < 256; ++m) {
      float rv = rows[r][m];
      float4 w4 = *(const float4*)&qw[m * 256 + c0];
      acc.x = fmaf(rv, w4.x, acc.x); acc.y = fmaf(rv, w4.y, acc.y);
      acc.z = fmaf(rv, w4.z, acc.z); acc.w = fmaf(rv, w4.w, acc.w);
    }
    float4 o; o.x = acc.x * SCALE; o.y = acc.y * SCALE; o.z = acc.z * SCALE; o.w = acc.w * SCALE;
    *(float4*)&qp[g * 256 + c0] = o;
  } else {
    // ---- cpb tables: one i per block, 1000 cells, 2 per thread ----
    float* w1 = (float*)smraw;          // 384
    float* b1 = w1 + 384;               // 128
    float* w2 = b1 + 128;               // 1024
    int i = bid - 320;
    for (int idx = t; idx < 384; idx += 512) w1[idx] = w1g[i * 384 + idx];
    if (t < 128) b1[t] = b1g[i * 128 + t];
    for (int idx = t; idx < 1024; idx += 512) w2[idx] = w2g[i * 1024 + idx];
    __syncthreads();
    for (int cell = t; cell < 1000; cell += 512) {
      int z = cell / 100, y = (cell / 10) % 10, x = cell % 10;
      const float step = 8.0f / 9.0f;
      float cz = -4.f + z * step, cy = -4.f + y * step, cx = -4.f + x * step;
      float o0 = 0, o1 = 0, o2 = 0, o3 = 0, o4 = 0, o5 = 0, o6 = 0, o7 = 0;
      for (int d = 0; d < 128; ++d) {
        float h = fmaxf(fmaf(cz, w1[d], fmaf(cy, w1[128 + d], fmaf(cx, w1[256 + d], b1[d]))), 0.f);
        const float* w2r = &w2[d * 8];
        o0 = fmaf(h, w2r[0], o0); o1 = fmaf(h, w2r[1], o1);
        o2 = fmaf(h, w2r[2], o2); o3 = fmaf(h, w2r[3], o3);
        o4 = fmaf(h, w2r[4], o4); o5 = fmaf(h, w2r[5], o5);
        o6 = fmaf(h, w2r[6], o6); o7 = fmaf(h, w2r[7], o7);
      }
      u16 r[8] = { f2bf(o0), f2bf(o1), f2bf(o2), f2bf(o3),
                   f2bf(o4), f2bf(o5), f2bf(o6), f2bf(o7) };
      *(uint4*)&tb[i * 8000 + cell * 8] = *(const uint4*)r;
    }
  }
}

// ---------------- kernel 1: fused qk + rpe + softmax -> attn ----------------
struct Axis { int o0, o1; float w0, w1; };

static __device__ __forceinline__ Axis axis_setup(float dv, int stride) {
  float g = copysignf(__log2f(fmaf(fabsf(dv), 512.f, 1.f)) * (1.f / 12.f), dv);
  float p = fmaf(g, 4.5f, 4.5f);
  float f = floorf(p);
  int i0 = (int)f;
  float w1v = p - f;
  float w0v = 1.f - w1v;
  Axis a;
  a.w0 = ((unsigned)i0 <= 9u) ? w0v : 0.f;
  a.w1 = ((unsigned)(i0 + 1) <= 9u) ? w1v : 0.f;
  int c0 = min(max(i0, 0), 9);
  int c1 = min(max(i0 + 1, 0), 9);
  a.o0 = c0 * stride;
  a.o1 = c1 * stride;
  return a;
}

#define DO_CORNER(U, W, J) do { float ww = (W); \
  acc[0][J] = fmaf(blo((U).x), ww, acc[0][J]); \
  acc[1][J] = fmaf(bhi((U).x), ww, acc[1][J]); \
  acc[2][J] = fmaf(blo((U).y), ww, acc[2][J]); \
  acc[3][J] = fmaf(bhi((U).y), ww, acc[3][J]); \
  acc[4][J] = fmaf(blo((U).z), ww, acc[4][J]); \
  acc[5][J] = fmaf(bhi((U).z), ww, acc[5][J]); \
  acc[6][J] = fmaf(blo((U).w), ww, acc[6][J]); \
  acc[7][J] = fmaf(bhi((U).w), ww, acc[7][J]); } while (0)

__global__ __launch_bounds__(1024, 4) void k_main(const u16* __restrict__ tbw,
                                                  const float* __restrict__ qp,
                                                  const float* __restrict__ kpT,
                                                  const float* __restrict__ xyz,
                                                  const float* __restrict__ refp,
                                                  float* __restrict__ attn) {
  __shared__ __align__(16) u16 tb[64000];    // 125 KB bf16 tables
  __shared__ __align__(16) float qrow[256];
  __shared__ __align__(16) float rp[24];
  __shared__ __align__(16) float red[128];   // [h][wave16]
  int t = threadIdx.x;
  int b = blockIdx.x >> 8, q = blockIdx.x & 255;
  for (int idx = t; idx < 8000; idx += 1024)
    ((uint4*)tb)[idx] = ((const uint4*)tbw)[idx];
  if (t < 64) ((float4*)qrow)[t] = ((const float4*)(qp + (b * 256 + q) * 256))[t];
  if (t >= 64 && t < 70) ((float4*)rp)[t - 64] = ((const float4*)(refp + (b * 256 + q) * 24))[t - 64];
  __syncthreads();

  float rpr[24];
  #pragma unroll
  for (int c4 = 0; c4 < 6; ++c4) {
    float4 v = *(const float4*)&rp[c4 * 4];
    rpr[c4 * 4 + 0] = v.x; rpr[c4 * 4 + 1] = v.y; rpr[c4 * 4 + 2] = v.z; rpr[c4 * 4 + 3] = v.w;
  }

  int wv = t >> 6, l = t & 63;         // 16 waves
  int k0 = wv * 128 + l * 2;           // 2 consecutive k per thread
  float acc[8][2] = {};

  // phase 1: qk^T (q pre-scaled)
  const float* kT = kpT + b * (32 * NK);
  #pragma unroll 1
  for (int dq = 0; dq < 8; ++dq) {
    const float* kp0 = kT + (dq * 4) * NK + k0;
    float2 kv0 = *(const float2*)(kp0);
    float2 kv1 = *(const float2*)(kp0 + NK);
    float2 kv2 = *(const float2*)(kp0 + 2 * NK);
    float2 kv3 = *(const float2*)(kp0 + 3 * NK);
    #pragma unroll
    for (int h = 0; h < 8; ++h) {
      float4 qv = *(const float4*)&qrow[h * 32 + dq * 4];
      acc[h][0] = fmaf(qv.x, kv0.x, fmaf(qv.y, kv1.x, fmaf(qv.z, kv2.x, fmaf(qv.w, kv3.x, acc[h][0]))));
      acc[h][1] = fmaf(qv.x, kv0.y, fmaf(qv.y, kv1.y, fmaf(qv.z, kv2.y, fmaf(qv.w, kv3.y, acc[h][1]))));
    }
  }

  // phase 2: rpe trilinear sampling, accumulate into logits
  #pragma unroll
  for (int j = 0; j < 2; ++j) {
    int k = k0 + j;
    const float* xp = xyz + (b * NK + k) * 3;
    float xv = xp[0], yv = xp[1], zv = xp[2];
    #pragma unroll 1
    for (int i = 0; i < 8; ++i) {
      float dxv = rpr[i * 3 + 0] - xv;
      float dyv = rpr[i * 3 + 1] - yv;
      float dzv = rpr[i * 3 + 2] - zv;
      Axis ax = axis_setup(dxv, 8);
      Axis ay = axis_setup(dyv, 80);
      Axis az = axis_setup(dzv, 800);
      float w00 = az.w0 * ay.w0, w01 = az.w0 * ay.w1;
      float w10 = az.w1 * ay.w0, w11 = az.w1 * ay.w1;
      const u16* tp = tb + i * 8000;
      uint4 u;
      u = *(const uint4*)(tp + az.o0 + ay.o0 + ax.o0); DO_CORNER(u, w00 * ax.w0, j);
      u = *(const uint4*)(tp + az.o0 + ay.o0 + ax.o1); DO_CORNER(u, w00 * ax.w1, j);
      u = *(const uint4*)(tp + az.o0 + ay.o1 + ax.o0); DO_CORNER(u, w01 * ax.w0, j);
      u = *(const uint4*)(tp + az.o0 + ay.o1 + ax.o1); DO_CORNER(u, w01 * ax.w1, j);
      u = *(const uint4*)(tp + az.o1 + ay.o0 + ax.o0); DO_CORNER(u, w10 * ax.w0, j);
      u = *(const uint4*)(tp + az.o1 + ay.o0 + ax.o1); DO_CORNER(u, w10 * ax.w1, j);
      u = *(const uint4*)(tp + az.o1 + ay.o1 + ax.o0); DO_CORNER(u, w11 * ax.w0, j);
      u = *(const uint4*)(tp + az.o1 + ay.o1 + ax.o1); DO_CORNER(u, w11 * ax.w1, j);
    }
  }

  // phase 3: softmax over k (2048) per head
  float mx[8];
  #pragma unroll
  for (int h = 0; h < 8; ++h) {
    float m = fmaxf(acc[h][0], acc[h][1]);
    #pragma unroll
    for (int off = 32; off >= 1; off >>= 1) m = fmaxf(m, __shfl_xor(m, off, 64));
    mx[h] = m;
  }
  if (l == 0) {
    #pragma unroll
    for (int h = 0; h < 8; ++h) red[h * 16 + wv] = mx[h];
  }
  __syncthreads();
  #pragma unroll
  for (int h = 0; h < 8; ++h) {
    float m = -1e30f;
    #pragma unroll
    for (int c4 = 0; c4 < 4; ++c4) {
      float4 r4 = *(const float4*)&red[h * 16 + c4 * 4];
      m = fmaxf(m, fmaxf(fmaxf(r4.x, r4.y), fmaxf(r4.z, r4.w)));
    }
    mx[h] = m;
  }
  __syncthreads();
  float sm[8];
  #pragma unroll
  for (int h = 0; h < 8; ++h) {
    acc[h][0] = __expf(acc[h][0] - mx[h]);
    acc[h][1] = __expf(acc[h][1] - mx[h]);
    float s = acc[h][0] + acc[h][1];
    #pragma unroll
    for (int off = 32; off >= 1; off >>= 1) s += __shfl_xor(s, off, 64);
    sm[h] = s;
  }
  if (l == 0) {
    #pragma unroll
    for (int h = 0; h < 8; ++h) red[h * 16 + wv] = sm[h];
  }
  __syncthreads();
  #pragma unroll
  for (int h = 0; h < 8; ++h) {
    float s = 0.f;
    #pragma unroll
    for (int c4 = 0; c4 < 4; ++c4) {
      float4 r4 = *(const float4*)&red[h * 16 + c4 * 4];
      s += (r4.x + r4.y) + (r4.z + r4.w);
    }
    float inv = 1.f / s;
    float2 pv;
    pv.x = acc[h][0] * inv; pv.y = acc[h][1] * inv;
    *(float2*)&attn[((b * 8 + h) * 256 + q) * 2048 + k0] = pv;
  }
}

// ---------------- kernel 2: x = attn @ v (full-k, direct) ----------------
__global__ __launch_bounds__(256) void k_av(const float* __restrict__ attn,
                                            const float* __restrict__ vp,
                                            float* __restrict__ x) {
  int bid = blockIdx.x;
  int qt = bid & 31, h = (bid >> 5) & 7, b = bid >> 8;
  int t = threadIdx.x;
  int rq = t >> 5, d = t & 31;
  int q = qt * 8 + rq;
  const float* ar = attn + ((b * 8 + h) * 256 + q) * 2048;
  const float* vb = vp + b * NK * 32 + d;
  float a0 = 0, a1 = 0, a2 = 0, a3 = 0;
  #pragma unroll 2
  for (int k = 0; k < 2048; k += 4) {
    float4 p = *(const float4*)&ar[k];
    a0 = fmaf(p.x, vb[(k + 0) * 32], a0);
    a1 = fmaf(p.y, vb[(k + 1) * 32], a1);
    a2 = fmaf(p.z, vb[(k + 2) * 32], a2);
    a3 = fmaf(p.w, vb[(k + 3) * 32], a3);
  }
  x[(b * 256 + q) * 256 + h * 32 + d] = (a0 + a1) + (a2 + a3);
}

// ---------------- kernel 3: out = x @ proj_w + proj_b ----------------
__global__ __launch_bounds__(256) void k_out(const float* __restrict__ x,
                                             const float* __restrict__ pw,
                                             const float* __restrict__ pb,
                                             float* __restrict__ out) {
  __shared__ float xr[4][257];
  int b = blockIdx.x >> 6, qc = blockIdx.x & 63, t = threadIdx.x;
  for (int idx = t; idx < 1024; idx += 256) {
    int r = idx >> 8, m = idx & 255;
    int q = qc * 4 + r;
    xr[r][m] = x[(b * 256 + q) * 256 + m];
  }
  __syncthreads();
  int r = t >> 6, c0 = (t & 63) * 4;
  float4 a = *(const float4*)&pb[c0];
  #pragma unroll 4
  for (int m = 0; m < 256; ++m) {
    float rv = xr[r][m];
    float4 w4 = *(const float4*)&pw[m * 256 + c0];
    a.x = fmaf(rv, w4.x, a.x); a.y = fmaf(rv, w4.y, a.y);
    a.z = fmaf(rv, w4.z, a.z); a.w = fmaf(rv, w4.w, a.w);
  }
  int q = qc * 4 + r;
  *(float4*)&out[(q * BB + b) * 256 + c0] = a;
}

// ---------------- launch ----------------
extern "C" void kernel_launch(void* const* d_in, const int* in_sizes, int n_in,
                              void* d_out, int out_size, void* d_ws, size_t ws_size,
                              hipStream_t stream) {
  const float* query = (const float*)d_in[0];
  const float* key   = (const float*)d_in[1];
  const float* refp  = (const float*)d_in[2];
  // d_in[3] reference_angle: unused by reference
  const float* xyz   = (const float*)d_in[4];
  const float* qw    = (const float*)d_in[5];
  const float* qb    = (const float*)d_in[6];
  const float* kw    = (const float*)d_in[7];
  const float* kb    = (const float*)d_in[8];
  const float* vw    = (const float*)d_in[9];
  const float* vb    = (const float*)d_in[10];
  const float* pw    = (const float*)d_in[11];
  const float* pb    = (const float*)d_in[12];
  const float* w1    = (const float*)d_in[13];
  const float* b1    = (const float*)d_in[14];
  const float* w2    = (const float*)d_in[15];

  char* ws = (char*)d_ws;
  u16*   tb  = (u16*)(ws + TB_OFF);
  float* qp  = (float*)(ws + QP_OFF);
  float* kpT = (float*)(ws + KT_OFF);
  float* vp  = (float*)(ws + VP_OFF);
  float* x   = (float*)(ws + X_OFF);
  float* out  = (float*)d_out;
  float* attn = out + 131072;  // second tuple output

  hipLaunchKernelGGL(k_prep, dim3(328), dim3(512),  0, stream,
                     query, key, qw, qb, kw, kb, vw, vb, w1, b1, w2, tb, qp, kpT, vp);
  hipLaunchKernelGGL(k_main, dim3(512), dim3(1024), 0, stream, tb, qp, kpT, xyz, refp, attn);
  hipLaunchKernelGGL(k_av,   dim3(512), dim3(256),  0, stream, attn, vp, x);
  hipLaunchKernelGGL(k_out,  dim3(128), dim3(256),  0, stream, x, pw, pb, out);
}

// Round 3
// 260.650 us; speedup vs baseline: 1.1676x; 1.1676x over previous
//
#include <hip/hip_runtime.h>
#include <hip/hip_bf16.h>
#include <cstdint>

#define NQ 256
#define NK 2048
#define BB 2
#define SCALE 0.17677669529663687f  // 32^-0.5

// ws byte offsets (16B aligned)
#define TB_OFF 0u         // ushort[64000]  bf16 tables [i][z][y][x][h]   128000 B
#define QP_OFF 128000u    // float[131072]  q-proj (B,nQ,256), pre-scaled 524288 B
#define KT_OFF 652288u    // float[131072]  k-proj transposed (B,32,nK)   524288 B
#define VP_OFF 1176576u   // float[131072]  v-proj (B,nK,32)              524288 B
#define X_OFF  1700864u   // float[2][131072] attn@v k-split partials     1 MB

typedef unsigned short u16;

static __device__ __forceinline__ float blo(uint32_t u) { return __uint_as_float(u << 16); }
static __device__ __forceinline__ float bhi(uint32_t u) { return __uint_as_float(u & 0xffff0000u); }

static __device__ __forceinline__ u16 f2bf(float f) {
  union { float f; uint32_t u; } v; v.f = f;
  uint32_t r = (v.u + 0x7fffu + ((v.u >> 16) & 1u)) >> 16;
  return (u16)r;
}

// ---------------- kernel 0: fused prep (tables + kv-proj + q-proj) ----------------
// blocks [0,256): kv-proj   [256,320): q-proj   [320,328): cpb tables
__global__ __launch_bounds__(512) void k_prep(const float* __restrict__ query,
                                              const float* __restrict__ key,
                                              const float* __restrict__ qw,
                                              const float* __restrict__ qb,
                                              const float* __restrict__ kw,
                                              const float* __restrict__ kb,
                                              const float* __restrict__ vw,
                                              const float* __restrict__ vb,
                                              const float* __restrict__ w1g,
                                              const float* __restrict__ b1g,
                                              const float* __restrict__ w2g,
                                              u16* __restrict__ tb,
                                              float* __restrict__ qp,
                                              float* __restrict__ kpT,
                                              float* __restrict__ vp) {
  __shared__ __align__(16) char smraw[16 * 257 * 4];
  int bid = blockIdx.x, t = threadIdx.x;

  if (bid < 256) {
    // ---- kv-proj: kpT[b][d][k] (LDS-transposed write), vp[b][k][d] ----
    float (*rows)[257] = (float(*)[257])smraw;
    int b = bid >> 7, kc = bid & 127;
    for (int idx = t; idx < 4096; idx += 512) {
      int r = idx >> 8, m = idx & 255;
      rows[r][m] = key[((kc * 16 + r) * BB + b) * 256 + m];
    }
    __syncthreads();
    int ks = t >> 5, d = t & 31;
    float a = kb[d], av = vb[d];
    #pragma unroll 4
    for (int m = 0; m < 256; ++m) {
      float rv = rows[ks][m];
      a  = fmaf(rv, kw[m * 32 + d], a);
      av = fmaf(rv, vw[m * 32 + d], av);
    }
    int k = kc * 16 + ks;
    vp[(b * NK + k) * 32 + d] = av;
    __syncthreads();                       // rows no longer needed
    float* flat = (float*)smraw;
    flat[d * 16 + ks] = a;
    __syncthreads();
    int dd = t >> 4, kk = t & 15;          // t < 512 covers 32x16
    kpT[(b * 32 + dd) * NK + kc * 16 + kk] = flat[dd * 16 + kk];
  } else if (bid < 320) {
    // ---- q-proj (pre-scaled): 8 rows per block ----
    float (*rows)[257] = (float(*)[257])smraw;
    int qg = bid - 256;  // 0..63, 8 global rows each
    for (int idx = t; idx < 2048; idx += 512) {
      int r = idx >> 8, m = idx & 255;
      int g = qg * 8 + r, b = g >> 8, q = g & 255;
      rows[r][m] = query[(q * BB + b) * 256 + m];
    }
    __syncthreads();
    int r = t >> 6, c0 = (t & 63) * 4;
    int g = qg * 8 + r;
    float4 acc = *(const float4*)&qb[c0];
    #pragma unroll 4
    for (int m = 0; m < 256; ++m) {
      float rv = rows[r][m];
      float4 w4 = *(const float4*)&qw[m * 256 + c0];
      acc.x = fmaf(rv, w4.x, acc.x); acc.y = fmaf(rv, w4.y, acc.y);
      acc.z = fmaf(rv, w4.z, acc.z); acc.w = fmaf(rv, w4.w, acc.w);
    }
    float4 o; o.x = acc.x * SCALE; o.y = acc.y * SCALE; o.z = acc.z * SCALE; o.w = acc.w * SCALE;
    *(float4*)&qp[g * 256 + c0] = o;
  } else {
    // ---- cpb tables: one i per block ----
    float* w1 = (float*)smraw;          // 384
    float* b1 = w1 + 384;               // 128
    float* w2 = b1 + 128;               // 1024
    int i = bid - 320;
    for (int idx = t; idx < 384; idx += 512) w1[idx] = w1g[i * 384 + idx];
    if (t < 128) b1[t] = b1g[i * 128 + t];
    for (int idx = t; idx < 1024; idx += 512) w2[idx] = w2g[i * 1024 + idx];
    __syncthreads();
    for (int cell = t; cell < 1000; cell += 512) {
      int z = cell / 100, y = (cell / 10) % 10, x = cell % 10;
      const float step = 8.0f / 9.0f;
      float cz = -4.f + z * step, cy = -4.f + y * step, cx = -4.f + x * step;
      float o0 = 0, o1 = 0, o2 = 0, o3 = 0, o4 = 0, o5 = 0, o6 = 0, o7 = 0;
      for (int d = 0; d < 128; ++d) {
        float h = fmaxf(fmaf(cz, w1[d], fmaf(cy, w1[128 + d], fmaf(cx, w1[256 + d], b1[d]))), 0.f);
        const float* w2r = &w2[d * 8];
        o0 = fmaf(h, w2r[0], o0); o1 = fmaf(h, w2r[1], o1);
        o2 = fmaf(h, w2r[2], o2); o3 = fmaf(h, w2r[3], o3);
        o4 = fmaf(h, w2r[4], o4); o5 = fmaf(h, w2r[5], o5);
        o6 = fmaf(h, w2r[6], o6); o7 = fmaf(h, w2r[7], o7);
      }
      u16 r[8] = { f2bf(o0), f2bf(o1), f2bf(o2), f2bf(o3),
                   f2bf(o4), f2bf(o5), f2bf(o6), f2bf(o7) };
      *(uint4*)&tb[i * 8000 + cell * 8] = *(const uint4*)r;
    }
  }
}

// ---------------- kernel 1: fused qk + rpe + softmax -> attn ----------------
struct Axis { int o0, o1; float w0, w1; };

static __device__ __forceinline__ Axis axis_setup(float dv, int stride) {
  float g = copysignf(__log2f(fmaf(fabsf(dv), 512.f, 1.f)) * (1.f / 12.f), dv);
  float p = fmaf(g, 4.5f, 4.5f);
  float f = floorf(p);
  int i0 = (int)f;
  float w1v = p - f;
  float w0v = 1.f - w1v;
  Axis a;
  a.w0 = ((unsigned)i0 <= 9u) ? w0v : 0.f;
  a.w1 = ((unsigned)(i0 + 1) <= 9u) ? w1v : 0.f;
  int c0 = min(max(i0, 0), 9);
  int c1 = min(max(i0 + 1, 0), 9);
  a.o0 = c0 * stride;
  a.o1 = c1 * stride;
  return a;
}

#define DO_CORNER(U, W, J) do { float ww = (W); \
  acc[0][J] = fmaf(blo((U).x), ww, acc[0][J]); \
  acc[1][J] = fmaf(bhi((U).x), ww, acc[1][J]); \
  acc[2][J] = fmaf(blo((U).y), ww, acc[2][J]); \
  acc[3][J] = fmaf(bhi((U).y), ww, acc[3][J]); \
  acc[4][J] = fmaf(blo((U).z), ww, acc[4][J]); \
  acc[5][J] = fmaf(bhi((U).z), ww, acc[5][J]); \
  acc[6][J] = fmaf(blo((U).w), ww, acc[6][J]); \
  acc[7][J] = fmaf(bhi((U).w), ww, acc[7][J]); } while (0)

__global__ __launch_bounds__(1024, 4) void k_main(const u16* __restrict__ tbw,
                                                  const float* __restrict__ qp,
                                                  const float* __restrict__ kpT,
                                                  const float* __restrict__ xyz,
                                                  const float* __restrict__ refp,
                                                  float* __restrict__ attn) {
  __shared__ __align__(16) u16 tb[64000];     // 125 KB bf16 tables
  __shared__ __align__(16) float qrow[2][256];
  __shared__ __align__(16) float rp[2][24];
  __shared__ __align__(16) float red[2][64];  // [qh][h][wave8]
  int t = threadIdx.x;
  int b = blockIdx.x >> 7, qc = blockIdx.x & 127;
  for (int idx = t; idx < 8000; idx += 1024)
    ((uint4*)tb)[idx] = ((const uint4*)tbw)[idx];
  if (t < 128) {
    int qh2 = t >> 6, c = t & 63;
    ((float4*)qrow[qh2])[c] = ((const float4*)(qp + (b * 256 + qc * 2 + qh2) * 256))[c];
  } else if (t < 140) {
    int idx = t - 128;                 // 12 float4s cover rp[2][24]
    int qh2 = idx / 6, c = idx % 6;
    ((float4*)rp[qh2])[c] = ((const float4*)(refp + (b * 256 + qc * 2 + qh2) * 24))[c];
  }
  __syncthreads();

  int wv = t >> 6, l = t & 63;
  int qh = wv >> 3, wvl = wv & 7;
  int q = qc * 2 + qh;
  int k0 = wvl * 256 + l * 4;          // 4 consecutive k per thread
  float acc[8][4] = {};

  // phase 1: qk^T (q pre-scaled)
  const float* kT = kpT + b * (32 * NK);
  #pragma unroll 1
  for (int dq = 0; dq < 8; ++dq) {
    const float* kp0 = kT + (dq * 4) * NK + k0;
    float4 kv0 = *(const float4*)(kp0);
    float4 kv1 = *(const float4*)(kp0 + NK);
    float4 kv2 = *(const float4*)(kp0 + 2 * NK);
    float4 kv3 = *(const float4*)(kp0 + 3 * NK);
    #pragma unroll
    for (int h = 0; h < 8; ++h) {
      float4 qv = *(const float4*)&qrow[qh][h * 32 + dq * 4];
      acc[h][0] = fmaf(qv.x, kv0.x, fmaf(qv.y, kv1.x, fmaf(qv.z, kv2.x, fmaf(qv.w, kv3.x, acc[h][0]))));
      acc[h][1] = fmaf(qv.x, kv0.y, fmaf(qv.y, kv1.y, fmaf(qv.z, kv2.y, fmaf(qv.w, kv3.y, acc[h][1]))));
      acc[h][2] = fmaf(qv.x, kv0.z, fmaf(qv.y, kv1.z, fmaf(qv.z, kv2.z, fmaf(qv.w, kv3.z, acc[h][2]))));
      acc[h][3] = fmaf(qv.x, kv0.w, fmaf(qv.y, kv1.w, fmaf(qv.z, kv2.w, fmaf(qv.w, kv3.w, acc[h][3]))));
    }
  }

  // phase 2: rpe trilinear sampling, accumulate into logits
  {
    const float* xp = xyz + (size_t)(b * NK + k0) * 3;
    float4 X0 = *(const float4*)(xp);
    float4 X1 = *(const float4*)(xp + 4);
    float4 X2 = *(const float4*)(xp + 8);
    float xv[4] = { X0.x, X0.w, X1.z, X2.y };
    float yv[4] = { X0.y, X1.x, X1.w, X2.z };
    float zv[4] = { X0.z, X1.y, X2.x, X2.w };
    #pragma unroll 1
    for (int i = 0; i < 8; ++i) {
      float rx = rp[qh][i * 3 + 0];
      float ry = rp[qh][i * 3 + 1];
      float rz = rp[qh][i * 3 + 2];
      const u16* tp = tb + i * 8000;
      #pragma unroll
      for (int j = 0; j < 4; ++j) {
        Axis ax = axis_setup(rx - xv[j], 8);
        Axis ay = axis_setup(ry - yv[j], 80);
        Axis az = axis_setup(rz - zv[j], 800);
        float w00 = az.w0 * ay.w0, w01 = az.w0 * ay.w1;
        float w10 = az.w1 * ay.w0, w11 = az.w1 * ay.w1;
        uint4 u;
        u = *(const uint4*)(tp + az.o0 + ay.o0 + ax.o0); DO_CORNER(u, w00 * ax.w0, j);
        u = *(const uint4*)(tp + az.o0 + ay.o0 + ax.o1); DO_CORNER(u, w00 * ax.w1, j);
        u = *(const uint4*)(tp + az.o0 + ay.o1 + ax.o0); DO_CORNER(u, w01 * ax.w0, j);
        u = *(const uint4*)(tp + az.o0 + ay.o1 + ax.o1); DO_CORNER(u, w01 * ax.w1, j);
        u = *(const uint4*)(tp + az.o1 + ay.o0 + ax.o0); DO_CORNER(u, w10 * ax.w0, j);
        u = *(const uint4*)(tp + az.o1 + ay.o0 + ax.o1); DO_CORNER(u, w10 * ax.w1, j);
        u = *(const uint4*)(tp + az.o1 + ay.o1 + ax.o0); DO_CORNER(u, w11 * ax.w0, j);
        u = *(const uint4*)(tp + az.o1 + ay.o1 + ax.o1); DO_CORNER(u, w11 * ax.w1, j);
      }
    }
  }

  // phase 3: softmax over k (2048) per head, within each wave-half (8 waves)
  float mx[8];
  #pragma unroll
  for (int h = 0; h < 8; ++h) {
    float m = fmaxf(fmaxf(acc[h][0], acc[h][1]), fmaxf(acc[h][2], acc[h][3]));
    #pragma unroll
    for (int off = 32; off >= 1; off >>= 1) m = fmaxf(m, __shfl_xor(m, off, 64));
    mx[h] = m;
  }
  if (l == 0) {
    #pragma unroll
    for (int h = 0; h < 8; ++h) red[qh][h * 8 + wvl] = mx[h];
  }
  __syncthreads();
  #pragma unroll
  for (int h = 0; h < 8; ++h) {
    float4 r0 = *(const float4*)&red[qh][h * 8];
    float4 r1 = *(const float4*)&red[qh][h * 8 + 4];
    mx[h] = fmaxf(fmaxf(fmaxf(r0.x, r0.y), fmaxf(r0.z, r0.w)),
                  fmaxf(fmaxf(r1.x, r1.y), fmaxf(r1.z, r1.w)));
  }
  __syncthreads();
  float sm[8];
  #pragma unroll
  for (int h = 0; h < 8; ++h) {
    acc[h][0] = __expf(acc[h][0] - mx[h]);
    acc[h][1] = __expf(acc[h][1] - mx[h]);
    acc[h][2] = __expf(acc[h][2] - mx[h]);
    acc[h][3] = __expf(acc[h][3] - mx[h]);
    float s = (acc[h][0] + acc[h][1]) + (acc[h][2] + acc[h][3]);
    #pragma unroll
    for (int off = 32; off >= 1; off >>= 1) s += __shfl_xor(s, off, 64);
    sm[h] = s;
  }
  if (l == 0) {
    #pragma unroll
    for (int h = 0; h < 8; ++h) red[qh][h * 8 + wvl] = sm[h];
  }
  __syncthreads();
  #pragma unroll
  for (int h = 0; h < 8; ++h) {
    float4 r0 = *(const float4*)&red[qh][h * 8];
    float4 r1 = *(const float4*)&red[qh][h * 8 + 4];
    float s = ((r0.x + r0.y) + (r0.z + r0.w)) + ((r1.x + r1.y) + (r1.z + r1.w));
    float inv = 1.f / s;
    float4 pv;
    pv.x = acc[h][0] * inv; pv.y = acc[h][1] * inv;
    pv.z = acc[h][2] * inv; pv.w = acc[h][3] * inv;
    *(float4*)&attn[((b * 8 + h) * 256 + q) * 2048 + k0] = pv;
  }
}

// ---------------- kernel 2: x = attn @ v (k-split x2 partials) ----------------
__global__ __launch_bounds__(256) void k_av(const float* __restrict__ attn,
                                            const float* __restrict__ vp,
                                            float* __restrict__ xpart) {
  int bid = blockIdx.x;
  int kh = bid & 1, qt = (bid >> 1) & 31, h = (bid >> 6) & 7, b = bid >> 9;
  int t = threadIdx.x;
  int rq = t >> 5, d = t & 31;
  int q = qt * 8 + rq;
  const float* ar = attn + ((size_t)((b * 8 + h) * 256 + q)) * 2048 + kh * 1024;
  const float* vb = vp + b * NK * 32 + kh * 1024 * 32 + d;
  float a0 = 0, a1 = 0, a2 = 0, a3 = 0, a4 = 0, a5 = 0, a6 = 0, a7 = 0;
  #pragma unroll 2
  for (int k = 0; k < 1024; k += 8) {
    float4 p0 = *(const float4*)&ar[k];
    float4 p1 = *(const float4*)&ar[k + 4];
    a0 = fmaf(p0.x, vb[(k + 0) * 32], a0);
    a1 = fmaf(p0.y, vb[(k + 1) * 32], a1);
    a2 = fmaf(p0.z, vb[(k + 2) * 32], a2);
    a3 = fmaf(p0.w, vb[(k + 3) * 32], a3);
    a4 = fmaf(p1.x, vb[(k + 4) * 32], a4);
    a5 = fmaf(p1.y, vb[(k + 5) * 32], a5);
    a6 = fmaf(p1.z, vb[(k + 6) * 32], a6);
    a7 = fmaf(p1.w, vb[(k + 7) * 32], a7);
  }
  float s = ((a0 + a1) + (a2 + a3)) + ((a4 + a5) + (a6 + a7));
  xpart[kh * 131072 + (b * 256 + q) * 256 + h * 32 + d] = s;
}

// ---------------- kernel 3: out = (xpart0+xpart1) @ proj_w + proj_b ----------------
__global__ __launch_bounds__(256) void k_out(const float* __restrict__ xpart,
                                             const float* __restrict__ pw,
                                             const float* __restrict__ pb,
                                             float* __restrict__ out) {
  __shared__ float xr[4][257];
  int b = blockIdx.x >> 6, qc = blockIdx.x & 63, t = threadIdx.x;
  for (int idx = t; idx < 1024; idx += 256) {
    int r = idx >> 8, m = idx & 255;
    int q = qc * 4 + r;
    int o = (b * 256 + q) * 256 + m;
    xr[r][m] = xpart[o] + xpart[131072 + o];
  }
  __syncthreads();
  int r = t >> 6, c0 = (t & 63) * 4;
  float4 a = *(const float4*)&pb[c0];
  #pragma unroll 4
  for (int m = 0; m < 256; ++m) {
    float rv = xr[r][m];
    float4 w4 = *(const float4*)&pw[m * 256 + c0];
    a.x = fmaf(rv, w4.x, a.x); a.y = fmaf(rv, w4.y, a.y);
    a.z = fmaf(rv, w4.z, a.z); a.w = fmaf(rv, w4.w, a.w);
  }
  int q = qc * 4 + r;
  *(float4*)&out[(q * BB + b) * 256 + c0] = a;
}

// ---------------- launch ----------------
extern "C" void kernel_launch(void* const* d_in, const int* in_sizes, int n_in,
                              void* d_out, int out_size, void* d_ws, size_t ws_size,
                              hipStream_t stream) {
  const float* query = (const float*)d_in[0];
  const float* key   = (const float*)d_in[1];
  const float* refp  = (const float*)d_in[2];
  // d_in[3] reference_angle: unused by reference
  const float* xyz   = (const float*)d_in[4];
  const float* qw    = (const float*)d_in[5];
  const float* qb    = (const float*)d_in[6];
  const float* kw    = (const float*)d_in[7];
  const float* kb    = (const float*)d_in[8];
  const float* vw    = (const float*)d_in[9];
  const float* vb    = (const float*)d_in[10];
  const float* pw    = (const float*)d_in[11];
  const float* pb    = (const float*)d_in[12];
  const float* w1    = (const float*)d_in[13];
  const float* b1    = (const float*)d_in[14];
  const float* w2    = (const float*)d_in[15];

  char* ws = (char*)d_ws;
  u16*   tb    = (u16*)(ws + TB_OFF);
  float* qp    = (float*)(ws + QP_OFF);
  float* kpT   = (float*)(ws + KT_OFF);
  float* vp    = (float*)(ws + VP_OFF);
  float* xpart = (float*)(ws + X_OFF);
  float* out  = (float*)d_out;
  float* attn = out + 131072;  // second tuple output

  hipLaunchKernelGGL(k_prep, dim3(328),  dim3(512),  0, stream,
                     query, key, qw, qb, kw, kb, vw, vb, w1, b1, w2, tb, qp, kpT, vp);
  hipLaunchKernelGGL(k_main, dim3(256),  dim3(1024), 0, stream, tb, qp, kpT, xyz, refp, attn);
  hipLaunchKernelGGL(k_av,   dim3(1024), dim3(256),  0, stream, attn, vp, xpart);
  hipLaunchKernelGGL(k_out,  dim3(128),  dim3(256),  0, stream, xpart, pw, pb, out);
}